// Round 8
// baseline (308.744 us; speedup 1.0000x reference)
//
#include <hip/hip_runtime.h>

// GQA forward on MI355X. bf16 MFMA everywhere, f32 accum.
// H=16 heads, G=4 groups, D=2048, HD=128, KV=512, bs=2, s=2048.
// Reference's _expand_kv is a RAW RESHAPE:
//   k[b,h,t',d] = Kp[b, h*128 + t'/16, (t'%4)*128 + d]   (same for v)
// => any 128-t' K/V tile = EIGHT 1KB Kp/Vp rows (8KB unique each).
//
// R8 changes:
//  - attn: QBLK=128 via 8-wave (512-thread) blocks; same 32KB K/V dbuf now
//    serves 2x q-rows (staging/q halved, 2 gld16/wave), grid 16x32=512.
//  - GEMMs: __launch_bounds__(256,3) -> 3 blocks/CU (m97's verified config).

#define DEV __device__ __forceinline__

typedef float f32x4 __attribute__((ext_vector_type(4)));
typedef __bf16 bf16x8 __attribute__((ext_vector_type(8)));

DEV f32x4 mfma16(bf16x8 a, bf16x8 b, f32x4 c) {
  return __builtin_amdgcn_mfma_f32_16x16x32_bf16(a, b, c, 0, 0, 0);
}

// async global->LDS, 16B/lane. LDS dest = wave-uniform base + lane*16;
// global source address is PER-LANE.
DEV void gld16(const void* gsrc, void* ldst) {
  __builtin_amdgcn_global_load_lds(
      (const __attribute__((address_space(1))) unsigned int*)gsrc,
      (__attribute__((address_space(3))) unsigned int*)ldst, 16, 0, 0);
}

// ---------------- X f32 -> bf16 ----------------
__global__ void convert_f32_bf16(const float* __restrict__ in, __bf16* __restrict__ out) {
  size_t i = ((size_t)blockIdx.x * 256 + threadIdx.x) * 8;
  float4 a = *(const float4*)(in + i);
  float4 b = *(const float4*)(in + i + 4);
  bf16x8 v;
  v[0] = (__bf16)a.x; v[1] = (__bf16)a.y; v[2] = (__bf16)a.z; v[3] = (__bf16)a.w;
  v[4] = (__bf16)b.x; v[5] = (__bf16)b.y; v[6] = (__bf16)b.z; v[7] = (__bf16)b.w;
  *(bf16x8*)(out + i) = v;
}

// ---------------- W [K][N] f32 -> WT [N][K] bf16 ----------------
__global__ void transpose_w_bf16(const float* __restrict__ W, __bf16* __restrict__ WT,
                                 int K, int N) {
  __shared__ float t[32][33];
  int tx = threadIdx.x & 31, ty = threadIdx.x >> 5;  // 32x8
  int n0 = blockIdx.x * 32, k0 = blockIdx.y * 32;
#pragma unroll
  for (int i = 0; i < 4; i++)
    t[ty + i * 8][tx] = W[(size_t)(k0 + ty + i * 8) * N + n0 + tx];
  __syncthreads();
#pragma unroll
  for (int i = 0; i < 4; i++)
    WT[(size_t)(n0 + ty + i * 8) * K + k0 + tx] = (__bf16)t[tx][ty + i * 8];
}

// ---------------- generic GEMM (O-proj): C = A * Bt^T + bias ----------------
template <int F32OUT>
__global__ __launch_bounds__(256, 3)
void gemm_bt(const __bf16* __restrict__ A, const __bf16* __restrict__ Bt,
             const float* __restrict__ bias, float scale, void* __restrict__ Cout,
             int M, int N, int K) {
  __shared__ __bf16 As[128 * 32];
  __shared__ __bf16 Bs[128 * 32];
  int tid = threadIdx.x, lane = tid & 63, w = tid >> 6;
  int wm = w >> 1, wn = w & 1, lg = lane >> 4, lc = lane & 15;
  int m0 = blockIdx.y * 128, n0 = blockIdx.x * 128;
  int srow = w * 16 + (lane >> 2), scol = (lane & 3) * 8;
  const __bf16* Ag = A + (size_t)(m0 + srow) * K + scol;
  const __bf16* Bg = Bt + (size_t)(n0 + srow) * K + scol;
  f32x4 acc[4][4] = {};
  int nk = K >> 5;
  for (int kt = 0; kt < nk; ++kt) {
    if (kt) __syncthreads();
    const __bf16* a = Ag + kt * 32;
    const __bf16* bp = Bg + kt * 32;
    gld16((void*)a, As + (w * 16) * 32);
    gld16((void*)(a + (size_t)64 * K), As + (64 + w * 16) * 32);
    gld16((void*)bp, Bs + (w * 16) * 32);
    gld16((void*)(bp + (size_t)64 * K), Bs + (64 + w * 16) * 32);
    __syncthreads();
    bf16x8 af[4], bf[4];
#pragma unroll
    for (int i = 0; i < 4; i++)
      af[i] = *(const bf16x8*)(As + (wm * 64 + i * 16 + lc) * 32 + lg * 8);
#pragma unroll
    for (int i = 0; i < 4; i++)
      bf[i] = *(const bf16x8*)(Bs + (wn * 64 + i * 16 + lc) * 32 + lg * 8);
#pragma unroll
    for (int mi = 0; mi < 4; mi++)
#pragma unroll
      for (int ni = 0; ni < 4; ni++)
        acc[mi][ni] = mfma16(af[mi], bf[ni], acc[mi][ni]);
  }
  float bcol[4];
#pragma unroll
  for (int ni = 0; ni < 4; ni++) bcol[ni] = bias[n0 + wn * 64 + ni * 16 + lc];
#pragma unroll
  for (int mi = 0; mi < 4; mi++)
#pragma unroll
    for (int ni = 0; ni < 4; ni++)
#pragma unroll
      for (int r = 0; r < 4; r++) {
        int row = m0 + wm * 64 + mi * 16 + lg * 4 + r;
        int col = n0 + wn * 64 + ni * 16 + lc;
        float v = (acc[mi][ni][r] + bcol[ni]) * scale;
        if (F32OUT)
          ((float*)Cout)[(size_t)row * N + col] = v;
        else
          ((__bf16*)Cout)[(size_t)row * N + col] = (__bf16)v;
      }
}

// ---------------- fused QKV projection: N=3072 (2048 Q | 512 K | 512 V) ----------------
__global__ __launch_bounds__(256, 3)
void gemm_qkv(const __bf16* __restrict__ A, const __bf16* __restrict__ Bt,
              const float* __restrict__ bq, const float* __restrict__ bk,
              const float* __restrict__ bv, float qscale,
              __bf16* __restrict__ Qo, __bf16* __restrict__ Ko, __bf16* __restrict__ Vo) {
  const int K = 2048;
  __shared__ __bf16 As[128 * 32];
  __shared__ __bf16 Bs[128 * 32];
  int tid = threadIdx.x, lane = tid & 63, w = tid >> 6;
  int wm = w >> 1, wn = w & 1, lg = lane >> 4, lc = lane & 15;
  int m0 = blockIdx.y * 128, n0 = blockIdx.x * 128;
  int srow = w * 16 + (lane >> 2), scol = (lane & 3) * 8;
  const __bf16* Ag = A + (size_t)(m0 + srow) * K + scol;
  const __bf16* Bg = Bt + (size_t)(n0 + srow) * K + scol;
  f32x4 acc[4][4] = {};
  for (int kt = 0; kt < 64; ++kt) {
    if (kt) __syncthreads();
    const __bf16* a = Ag + kt * 32;
    const __bf16* bp = Bg + kt * 32;
    gld16((void*)a, As + (w * 16) * 32);
    gld16((void*)(a + (size_t)64 * K), As + (64 + w * 16) * 32);
    gld16((void*)bp, Bs + (w * 16) * 32);
    gld16((void*)(bp + (size_t)64 * K), Bs + (64 + w * 16) * 32);
    __syncthreads();
    bf16x8 af[4], bf[4];
#pragma unroll
    for (int i = 0; i < 4; i++)
      af[i] = *(const bf16x8*)(As + (wm * 64 + i * 16 + lc) * 32 + lg * 8);
#pragma unroll
    for (int i = 0; i < 4; i++)
      bf[i] = *(const bf16x8*)(Bs + (wn * 64 + i * 16 + lc) * 32 + lg * 8);
#pragma unroll
    for (int mi = 0; mi < 4; mi++)
#pragma unroll
      for (int ni = 0; ni < 4; ni++)
        acc[mi][ni] = mfma16(af[mi], bf[ni], acc[mi][ni]);
  }
  // region select (block-uniform)
  const float* bp;
  __bf16* op;
  int ldc, c0;
  float scl;
  if (n0 < 2048) { bp = bq; op = Qo; ldc = 2048; c0 = n0; scl = qscale; }
  else if (n0 < 2560) { bp = bk; op = Ko; ldc = 512; c0 = n0 - 2048; scl = 1.f; }
  else { bp = bv; op = Vo; ldc = 512; c0 = n0 - 2560; scl = 1.f; }
  float bcol[4];
#pragma unroll
  for (int ni = 0; ni < 4; ni++) bcol[ni] = bp[c0 + wn * 64 + ni * 16 + lc];
#pragma unroll
  for (int mi = 0; mi < 4; mi++)
#pragma unroll
    for (int ni = 0; ni < 4; ni++)
#pragma unroll
      for (int r = 0; r < 4; r++) {
        int row = m0 + wm * 64 + mi * 16 + lg * 4 + r;
        int col = c0 + wn * 64 + ni * 16 + lc;
        op[(size_t)row * ldc + col] = (__bf16)((acc[mi][ni][r] + bcol[ni]) * scl);
      }
}

// ---------------- build reordered+swizzled Vc ----------------
// Vc block (bh, kt128) is 8KB: element (d, kslot) at byte
//   d*64 + ((kslot*2) ^ (((d>>1)&3)<<4)),  value = Vp[b*2048+h*128+kt*8 + (kslot&7)][(kslot>>3)*128 + d]
__global__ void expand_vc(const __bf16* __restrict__ Vp, __bf16* __restrict__ Vc) {
  __shared__ __bf16 Vl[8][512];
  int tid = threadIdx.x;
  int kt = blockIdx.x, bh = blockIdx.y, b = bh >> 4, h = bh & 15;
  size_t base = (size_t)b * 2048 + h * 128 + kt * 8;
#pragma unroll
  for (int i = 0; i < 2; ++i) {
    int idx = i * 256 + tid;  // 512 float4s
    int rr = idx >> 6, ch = idx & 63;
    *(float4*)(&Vl[rr][ch * 8]) = *(const float4*)(Vp + (base + rr) * 512 + ch * 8);
  }
  __syncthreads();
  __bf16* out = Vc + ((size_t)(bh * 16 + kt)) * 4096;
#pragma unroll
  for (int i = 0; i < 2; ++i) {
    int u = i * 256 + tid;  // 512 16B-units
    int d = u >> 2, m = u & 3;
    int seg = m ^ ((d >> 1) & 3);
    bf16x8 val;
#pragma unroll
    for (int j = 0; j < 8; j++) val[j] = Vl[j][seg * 128 + d];
    *(bf16x8*)(out + u * 8) = val;
  }
}

// ---------------- flash attention, causal, fold-PV, 8-wave QBLK=128 ----------------
// block = 8 waves (512 thr), QBLK=128 (16 q/wave), KVBLK=128, LDS 32KB dbuf.
// Q pre-scaled by log2e/sqrt(128); exp2 softmax, swapped QK^T with permuted
// K rows: s[nt][r] = S[t'=nt*16+r*4+lg][q=lc]. Fold in-lane; PV via Vc.
__global__ __launch_bounds__(512, 4)
void attn_fwd(const __bf16* __restrict__ Qb, const __bf16* __restrict__ Kp,
              const __bf16* __restrict__ VcG, __bf16* __restrict__ attO) {
  __shared__ alignas(16) char Kl[2][8192];   // 8 Kp rows, seg-XOR swizzled
  __shared__ alignas(16) char Vld[2][8192];  // Vc block (pre-swizzled in global)
  int tid = threadIdx.x, lane = tid & 63, w = tid >> 6;  // w = 0..7
  int lg = lane >> 4, lc = lane & 15;
  int qt = 15 - (int)blockIdx.x;  // heavy blocks first
  int bh = blockIdx.y, b = bh >> 4, h = bh & 15;
  int q0 = qt * 128;
  int qg = q0 + w * 16 + lc;
  const __bf16* Qrow = Qb + (size_t)(b * 2048 + qg) * 2048 + h * 128 + lg * 8;
  bf16x8 qf[4];
#pragma unroll
  for (int ks = 0; ks < 4; ks++) qf[ks] = *(const bf16x8*)(Qrow + ks * 32);
  asm volatile("s_waitcnt vmcnt(0)" ::: "memory");  // drain Q loads before counted stages
  f32x4 o[8] = {};
  float mrow = -3.0e38f, lsum = 0.f;  // stats for q=lc (lsum = lg-partial)
  const char* KpB = (const char*)Kp + (size_t)(b * 2048 + h * 128) * 1024;  // 1KB rows
  const char* VgB = (const char*)VcG + (size_t)bh * 16 * 8192;
  int ktmax = qt;  // diagonal 128-tile index
  // K stage: src byte offset within a row carries the seg-XOR (seg = lane>>4)
  int ksw = (lane * 16) ^ ((lane >> 4) << 5);
  // K read: per-lane constants
  int seg = lc >> 2;
  int kro = seg * 256;
  int lg16 = lg * 16;
  int kswr[4];
#pragma unroll
  for (int ks = 0; ks < 4; ks++) kswr[ks] = (ks * 64 + lg16) ^ (seg << 5);
  // V read base (swizzle collapses: (dt*16+lc)&6 == lc&6)
  int vbase = lc * 64 + (lg16 ^ ((lc & 6) << 3));

  // 8 waves: wave w stages K row w (1KB) + V KB w. 2 gld16/wave per tile.
#define STAGE(bufi, ktile)                                                             \
  do {                                                                                 \
    gld16(KpB + (size_t)((ktile) * 8 + w) * 1024 + ksw, &Kl[bufi][w * 1024]);          \
    gld16(VgB + (size_t)(ktile) * 8192 + w * 1024 + lane * 16, &Vld[bufi][w * 1024]);  \
  } while (0)

  int cur = 0;
  STAGE(0, 0);
  for (int kt = 0; kt <= ktmax; ++kt) {
    if (kt < ktmax) {
      STAGE(cur ^ 1, kt + 1);
      asm volatile("s_waitcnt vmcnt(2)" ::: "memory");  // this tile landed; next in flight
    } else {
      asm volatile("s_waitcnt vmcnt(0)" ::: "memory");
    }
    __builtin_amdgcn_s_barrier();
    const char* Kc = Kl[cur];
    const char* Vc = Vld[cur];

    // QK^T (swapped, permuted rows): s[nt][r] = S[t'=nt*16+r*4+lg][q=lc]
    f32x4 s[8];
    __builtin_amdgcn_s_setprio(1);
#pragma unroll
    for (int nt = 0; nt < 8; nt++) {
      if (kt * 128 + nt * 16 <= q0 + w * 16 + 15) {  // wave-uniform liveness
        s[nt] = (f32x4){0.f, 0.f, 0.f, 0.f};
#pragma unroll
        for (int ks = 0; ks < 4; ks++) {
          bf16x8 kf = *(const bf16x8*)(Kc + nt * 1024 + kro + kswr[ks]);
          s[nt] = mfma16(kf, qf[ks], s[nt]);
        }
      } else {
        s[nt] = (f32x4){-3.0e38f, -3.0e38f, -3.0e38f, -3.0e38f};
      }
    }
    __builtin_amdgcn_s_setprio(0);
    if (kt == ktmax) {  // causal mask on diagonal 128-block
#pragma unroll
      for (int nt = 0; nt < 8; nt++)
#pragma unroll
        for (int r = 0; r < 4; r++)
          if (kt * 128 + nt * 16 + r * 4 + lg > qg) s[nt][r] = -3.0e38f;
    }
    // row max over all 128 t' for q=lc: in-lane 31 fmax + xor16/32
    float v = fmaxf(fmaxf(s[0][0], s[0][1]), fmaxf(s[0][2], s[0][3]));
#pragma unroll
    for (int nt = 1; nt < 8; nt++)
      v = fmaxf(v, fmaxf(fmaxf(s[nt][0], s[nt][1]), fmaxf(s[nt][2], s[nt][3])));
    v = fmaxf(v, __shfl_xor(v, 16));
    v = fmaxf(v, __shfl_xor(v, 32));
    if (__any(v > mrow + 8.0f)) {  // defer-max rescale (rare after first tile)
      float mn = fmaxf(mrow, v);
      float sc = exp2f(mrow - mn);
      mrow = mn;
      lsum *= sc;
#pragma unroll
      for (int r = 0; r < 4; r++) {
        float scr = __shfl(sc, lg * 4 + r);
#pragma unroll
        for (int dt = 0; dt < 8; dt++) o[dt][r] *= scr;
      }
    }
    // exp2 + in-lane fold: pf[nt] = Pfold[q=lc][k32 = nt*4 + lg]
    float pf[8];
    float rs = 0.f;
#pragma unroll
    for (int nt = 0; nt < 8; nt++) {
      float e0 = exp2f(s[nt][0] - mrow);
      float e1 = exp2f(s[nt][1] - mrow);
      float e2 = exp2f(s[nt][2] - mrow);
      float e3 = exp2f(s[nt][3] - mrow);
      pf[nt] = (e0 + e1) + (e2 + e3);
      rs += pf[nt];
    }
    lsum += rs;  // partial (this lane's lg-slice); reduced in epilogue
    bf16x8 af;
#pragma unroll
    for (int j = 0; j < 8; j++) af[j] = (__bf16)pf[j];
    // PV: o[16q][128d] += Pfold * Vm  (8 MFMAs, zero cross-lane)
    __builtin_amdgcn_s_setprio(1);
#pragma unroll
    for (int dt = 0; dt < 8; dt++) {
      bf16x8 vf = *(const bf16x8*)(Vc + dt * 1024 + vbase);
      o[dt] = mfma16(af, vf, o[dt]);
    }
    __builtin_amdgcn_s_setprio(0);
    __builtin_amdgcn_s_barrier();  // all waves done with buf[cur] before overwrite
    cur ^= 1;
  }
  // epilogue: reduce lg-partial row sums, divide, store bf16
  lsum += __shfl_xor(lsum, 16);
  lsum += __shfl_xor(lsum, 32);
  float inv = 1.0f / lsum;
#pragma unroll
  for (int r = 0; r < 4; r++) {
    float invr = __shfl(inv, lg * 4 + r);
    int row = b * 2048 + q0 + w * 16 + lg * 4 + r;
#pragma unroll
    for (int dt = 0; dt < 8; dt++)
      attO[(size_t)row * 2048 + h * 128 + dt * 16 + lc] = (__bf16)(o[dt][r] * invr);
  }
#undef STAGE
}

extern "C" void kernel_launch(void* const* d_in, const int* in_sizes, int n_in,
                              void* d_out, int out_size, void* d_ws, size_t ws_size,
                              hipStream_t stream) {
  const float* X = (const float*)d_in[0];
  const float* Wq = (const float*)d_in[1];
  const float* bq = (const float*)d_in[2];
  const float* Wk = (const float*)d_in[3];
  const float* bk = (const float*)d_in[4];
  const float* Wv = (const float*)d_in[5];
  const float* bv = (const float*)d_in[6];
  const float* Wo = (const float*)d_in[7];
  const float* bo = (const float*)d_in[8];
  char* ws = (char*)d_ws;
  const size_t MB = 1024 * 1024;
  __bf16* Xb     = (__bf16*)(ws + 0);        // 16 MB
  __bf16* WqkvT  = (__bf16*)(ws + 16 * MB);  // 12 MB (3072 x 2048)
  __bf16* WoT    = (__bf16*)(ws + 28 * MB);  // 8 MB
  __bf16* Qbf    = (__bf16*)(ws + 36 * MB);  // 16 MB
  __bf16* Kp     = (__bf16*)(ws + 52 * MB);  // 4 MB
  __bf16* Vp     = (__bf16*)(ws + 56 * MB);  // 4 MB
  __bf16* Vc     = (__bf16*)(ws + 60 * MB);  // 4 MB (reordered V)
  __bf16* aO     = (__bf16*)(ws + 64 * MB);  // 16 MB -> 80 MB total

  convert_f32_bf16<<<4096, 256, 0, stream>>>(X, Xb);
  transpose_w_bf16<<<dim3(64, 64), 256, 0, stream>>>(Wq, WqkvT, 2048, 2048);
  transpose_w_bf16<<<dim3(16, 64), 256, 0, stream>>>(Wk, WqkvT + (size_t)2048 * 2048, 2048, 512);
  transpose_w_bf16<<<dim3(16, 64), 256, 0, stream>>>(Wv, WqkvT + (size_t)2560 * 2048, 2048, 512);
  transpose_w_bf16<<<dim3(64, 64), 256, 0, stream>>>(Wo, WoT, 2048, 2048);

  // fold 1/sqrt(HD) * log2(e) into Q so softmax uses exp2 directly
  float qscale = 1.4426950408889634f * 0.08838834764831845f;
  gemm_qkv<<<dim3(24, 32), 256, 0, stream>>>(Xb, WqkvT, bq, bk, bv, qscale, Qbf, Kp, Vp);

  expand_vc<<<dim3(16, 32), 256, 0, stream>>>(Vp, Vc);
  attn_fwd<<<dim3(16, 32), 512, 0, stream>>>(Qbf, Kp, Vc, aO);

  gemm_bt<1><<<dim3(16, 32), 256, 0, stream>>>(aO, WoT, bo, 1.0f, (float*)d_out, 4096, 2048, 2048);
}

// Round 9
// 287.927 us; speedup vs baseline: 1.0723x; 1.0723x over previous
//
#include <hip/hip_runtime.h>

// GQA forward on MI355X. bf16 MFMA everywhere, f32 accum.
// H=16 heads, G=4 groups, D=2048, HD=128, KV=512, bs=2, s=2048.
// Reference's _expand_kv is a RAW RESHAPE:
//   k[b,h,t',d] = Kp[b, h*128 + t'/16, (t'%4)*128 + d]   (same for v)
// => any 128-t' K/V tile = EIGHT 1KB Kp/Vp rows (8KB unique each).
//
// R9 change (attn only): fix load imbalance. R8 grid (16,32) paired each CU
// with two SAME-qt blocks (makespan 32 tile-iters vs 17 avg). New grid
// (bh=32, slot=16) with qt = slot<8 ? 15-2*slot : 2*slot-16: CU c gets slots
// y and y+8 whose tile counts sum to 17 exactly -> uniform makespan.

#define DEV __device__ __forceinline__

typedef float f32x4 __attribute__((ext_vector_type(4)));
typedef __bf16 bf16x8 __attribute__((ext_vector_type(8)));

DEV f32x4 mfma16(bf16x8 a, bf16x8 b, f32x4 c) {
  return __builtin_amdgcn_mfma_f32_16x16x32_bf16(a, b, c, 0, 0, 0);
}

// async global->LDS, 16B/lane. LDS dest = wave-uniform base + lane*16;
// global source address is PER-LANE.
DEV void gld16(const void* gsrc, void* ldst) {
  __builtin_amdgcn_global_load_lds(
      (const __attribute__((address_space(1))) unsigned int*)gsrc,
      (__attribute__((address_space(3))) unsigned int*)ldst, 16, 0, 0);
}

// ---------------- X f32 -> bf16 ----------------
__global__ void convert_f32_bf16(const float* __restrict__ in, __bf16* __restrict__ out) {
  size_t i = ((size_t)blockIdx.x * 256 + threadIdx.x) * 8;
  float4 a = *(const float4*)(in + i);
  float4 b = *(const float4*)(in + i + 4);
  bf16x8 v;
  v[0] = (__bf16)a.x; v[1] = (__bf16)a.y; v[2] = (__bf16)a.z; v[3] = (__bf16)a.w;
  v[4] = (__bf16)b.x; v[5] = (__bf16)b.y; v[6] = (__bf16)b.z; v[7] = (__bf16)b.w;
  *(bf16x8*)(out + i) = v;
}

// ---------------- W [K][N] f32 -> WT [N][K] bf16 ----------------
__global__ void transpose_w_bf16(const float* __restrict__ W, __bf16* __restrict__ WT,
                                 int K, int N) {
  __shared__ float t[32][33];
  int tx = threadIdx.x & 31, ty = threadIdx.x >> 5;  // 32x8
  int n0 = blockIdx.x * 32, k0 = blockIdx.y * 32;
#pragma unroll
  for (int i = 0; i < 4; i++)
    t[ty + i * 8][tx] = W[(size_t)(k0 + ty + i * 8) * N + n0 + tx];
  __syncthreads();
#pragma unroll
  for (int i = 0; i < 4; i++)
    WT[(size_t)(n0 + ty + i * 8) * K + k0 + tx] = (__bf16)t[tx][ty + i * 8];
}

// ---------------- generic GEMM (O-proj): C = A * Bt^T + bias ----------------
template <int F32OUT>
__global__ __launch_bounds__(256, 3)
void gemm_bt(const __bf16* __restrict__ A, const __bf16* __restrict__ Bt,
             const float* __restrict__ bias, float scale, void* __restrict__ Cout,
             int M, int N, int K) {
  __shared__ __bf16 As[128 * 32];
  __shared__ __bf16 Bs[128 * 32];
  int tid = threadIdx.x, lane = tid & 63, w = tid >> 6;
  int wm = w >> 1, wn = w & 1, lg = lane >> 4, lc = lane & 15;
  int m0 = blockIdx.y * 128, n0 = blockIdx.x * 128;
  int srow = w * 16 + (lane >> 2), scol = (lane & 3) * 8;
  const __bf16* Ag = A + (size_t)(m0 + srow) * K + scol;
  const __bf16* Bg = Bt + (size_t)(n0 + srow) * K + scol;
  f32x4 acc[4][4] = {};
  int nk = K >> 5;
  for (int kt = 0; kt < nk; ++kt) {
    if (kt) __syncthreads();
    const __bf16* a = Ag + kt * 32;
    const __bf16* bp = Bg + kt * 32;
    gld16((void*)a, As + (w * 16) * 32);
    gld16((void*)(a + (size_t)64 * K), As + (64 + w * 16) * 32);
    gld16((void*)bp, Bs + (w * 16) * 32);
    gld16((void*)(bp + (size_t)64 * K), Bs + (64 + w * 16) * 32);
    __syncthreads();
    bf16x8 af[4], bf[4];
#pragma unroll
    for (int i = 0; i < 4; i++)
      af[i] = *(const bf16x8*)(As + (wm * 64 + i * 16 + lc) * 32 + lg * 8);
#pragma unroll
    for (int i = 0; i < 4; i++)
      bf[i] = *(const bf16x8*)(Bs + (wn * 64 + i * 16 + lc) * 32 + lg * 8);
#pragma unroll
    for (int mi = 0; mi < 4; mi++)
#pragma unroll
      for (int ni = 0; ni < 4; ni++)
        acc[mi][ni] = mfma16(af[mi], bf[ni], acc[mi][ni]);
  }
  float bcol[4];
#pragma unroll
  for (int ni = 0; ni < 4; ni++) bcol[ni] = bias[n0 + wn * 64 + ni * 16 + lc];
#pragma unroll
  for (int mi = 0; mi < 4; mi++)
#pragma unroll
    for (int ni = 0; ni < 4; ni++)
#pragma unroll
      for (int r = 0; r < 4; r++) {
        int row = m0 + wm * 64 + mi * 16 + lg * 4 + r;
        int col = n0 + wn * 64 + ni * 16 + lc;
        float v = (acc[mi][ni][r] + bcol[ni]) * scale;
        if (F32OUT)
          ((float*)Cout)[(size_t)row * N + col] = v;
        else
          ((__bf16*)Cout)[(size_t)row * N + col] = (__bf16)v;
      }
}

// ---------------- fused QKV projection: N=3072 (2048 Q | 512 K | 512 V) ----------------
__global__ __launch_bounds__(256, 3)
void gemm_qkv(const __bf16* __restrict__ A, const __bf16* __restrict__ Bt,
              const float* __restrict__ bq, const float* __restrict__ bk,
              const float* __restrict__ bv, float qscale,
              __bf16* __restrict__ Qo, __bf16* __restrict__ Ko, __bf16* __restrict__ Vo) {
  const int K = 2048;
  __shared__ __bf16 As[128 * 32];
  __shared__ __bf16 Bs[128 * 32];
  int tid = threadIdx.x, lane = tid & 63, w = tid >> 6;
  int wm = w >> 1, wn = w & 1, lg = lane >> 4, lc = lane & 15;
  int m0 = blockIdx.y * 128, n0 = blockIdx.x * 128;
  int srow = w * 16 + (lane >> 2), scol = (lane & 3) * 8;
  const __bf16* Ag = A + (size_t)(m0 + srow) * K + scol;
  const __bf16* Bg = Bt + (size_t)(n0 + srow) * K + scol;
  f32x4 acc[4][4] = {};
  for (int kt = 0; kt < 64; ++kt) {
    if (kt) __syncthreads();
    const __bf16* a = Ag + kt * 32;
    const __bf16* bp = Bg + kt * 32;
    gld16((void*)a, As + (w * 16) * 32);
    gld16((void*)(a + (size_t)64 * K), As + (64 + w * 16) * 32);
    gld16((void*)bp, Bs + (w * 16) * 32);
    gld16((void*)(bp + (size_t)64 * K), Bs + (64 + w * 16) * 32);
    __syncthreads();
    bf16x8 af[4], bf[4];
#pragma unroll
    for (int i = 0; i < 4; i++)
      af[i] = *(const bf16x8*)(As + (wm * 64 + i * 16 + lc) * 32 + lg * 8);
#pragma unroll
    for (int i = 0; i < 4; i++)
      bf[i] = *(const bf16x8*)(Bs + (wn * 64 + i * 16 + lc) * 32 + lg * 8);
#pragma unroll
    for (int mi = 0; mi < 4; mi++)
#pragma unroll
      for (int ni = 0; ni < 4; ni++)
        acc[mi][ni] = mfma16(af[mi], bf[ni], acc[mi][ni]);
  }
  // region select (block-uniform)
  const float* bp;
  __bf16* op;
  int ldc, c0;
  float scl;
  if (n0 < 2048) { bp = bq; op = Qo; ldc = 2048; c0 = n0; scl = qscale; }
  else if (n0 < 2560) { bp = bk; op = Ko; ldc = 512; c0 = n0 - 2048; scl = 1.f; }
  else { bp = bv; op = Vo; ldc = 512; c0 = n0 - 2560; scl = 1.f; }
  float bcol[4];
#pragma unroll
  for (int ni = 0; ni < 4; ni++) bcol[ni] = bp[c0 + wn * 64 + ni * 16 + lc];
#pragma unroll
  for (int mi = 0; mi < 4; mi++)
#pragma unroll
    for (int ni = 0; ni < 4; ni++)
#pragma unroll
      for (int r = 0; r < 4; r++) {
        int row = m0 + wm * 64 + mi * 16 + lg * 4 + r;
        int col = c0 + wn * 64 + ni * 16 + lc;
        op[(size_t)row * ldc + col] = (__bf16)((acc[mi][ni][r] + bcol[ni]) * scl);
      }
}

// ---------------- build reordered+swizzled Vc ----------------
// Vc block (bh, kt128) is 8KB: element (d, kslot) at byte
//   d*64 + ((kslot*2) ^ (((d>>1)&3)<<4)),  value = Vp[b*2048+h*128+kt*8 + (kslot&7)][(kslot>>3)*128 + d]
__global__ void expand_vc(const __bf16* __restrict__ Vp, __bf16* __restrict__ Vc) {
  __shared__ __bf16 Vl[8][512];
  int tid = threadIdx.x;
  int kt = blockIdx.x, bh = blockIdx.y, b = bh >> 4, h = bh & 15;
  size_t base = (size_t)b * 2048 + h * 128 + kt * 8;
#pragma unroll
  for (int i = 0; i < 2; ++i) {
    int idx = i * 256 + tid;  // 512 float4s
    int rr = idx >> 6, ch = idx & 63;
    *(float4*)(&Vl[rr][ch * 8]) = *(const float4*)(Vp + (base + rr) * 512 + ch * 8);
  }
  __syncthreads();
  __bf16* out = Vc + ((size_t)(bh * 16 + kt)) * 4096;
#pragma unroll
  for (int i = 0; i < 2; ++i) {
    int u = i * 256 + tid;  // 512 16B-units
    int d = u >> 2, m = u & 3;
    int seg = m ^ ((d >> 1) & 3);
    bf16x8 val;
#pragma unroll
    for (int j = 0; j < 8; j++) val[j] = Vl[j][seg * 128 + d];
    *(bf16x8*)(out + u * 8) = val;
  }
}

// ---------------- flash attention, causal, fold-PV, 8-wave QBLK=128 ----------------
// block = 8 waves (512 thr), QBLK=128 (16 q/wave), KVBLK=128, LDS 32KB dbuf.
// Q pre-scaled by log2e/sqrt(128); exp2 softmax, swapped QK^T with permuted
// K rows: s[nt][r] = S[t'=nt*16+r*4+lg][q=lc]. Fold in-lane; PV via Vc.
// Grid (bh=32, slot=16); qt from complementary pairing for uniform makespan.
__global__ __launch_bounds__(512, 4)
void attn_fwd(const __bf16* __restrict__ Qb, const __bf16* __restrict__ Kp,
              const __bf16* __restrict__ VcG, __bf16* __restrict__ attO) {
  __shared__ alignas(16) char Kl[2][8192];   // 8 Kp rows, seg-XOR swizzled
  __shared__ alignas(16) char Vld[2][8192];  // Vc block (pre-swizzled in global)
  int tid = threadIdx.x, lane = tid & 63, w = tid >> 6;  // w = 0..7
  int lg = lane >> 4, lc = lane & 15;
  int slot = (int)blockIdx.y;
  int qt = (slot < 8) ? (15 - 2 * slot) : (2 * slot - 16);  // pairs sum to 17 tiles
  int bh = blockIdx.x, b = bh >> 4, h = bh & 15;
  int q0 = qt * 128;
  int qg = q0 + w * 16 + lc;
  const __bf16* Qrow = Qb + (size_t)(b * 2048 + qg) * 2048 + h * 128 + lg * 8;
  bf16x8 qf[4];
#pragma unroll
  for (int ks = 0; ks < 4; ks++) qf[ks] = *(const bf16x8*)(Qrow + ks * 32);
  asm volatile("s_waitcnt vmcnt(0)" ::: "memory");  // drain Q loads before counted stages
  f32x4 o[8] = {};
  float mrow = -3.0e38f, lsum = 0.f;  // stats for q=lc (lsum = lg-partial)
  const char* KpB = (const char*)Kp + (size_t)(b * 2048 + h * 128) * 1024;  // 1KB rows
  const char* VgB = (const char*)VcG + (size_t)bh * 16 * 8192;
  int ktmax = qt;  // diagonal 128-tile index
  // K stage: src byte offset within a row carries the seg-XOR (seg = lane>>4)
  int ksw = (lane * 16) ^ ((lane >> 4) << 5);
  // K read: per-lane constants
  int seg = lc >> 2;
  int kro = seg * 256;
  int lg16 = lg * 16;
  int kswr[4];
#pragma unroll
  for (int ks = 0; ks < 4; ks++) kswr[ks] = (ks * 64 + lg16) ^ (seg << 5);
  // V read base (swizzle collapses: (dt*16+lc)&6 == lc&6)
  int vbase = lc * 64 + (lg16 ^ ((lc & 6) << 3));

  // 8 waves: wave w stages K row w (1KB) + V KB w. 2 gld16/wave per tile.
#define STAGE(bufi, ktile)                                                             \
  do {                                                                                 \
    gld16(KpB + (size_t)((ktile) * 8 + w) * 1024 + ksw, &Kl[bufi][w * 1024]);          \
    gld16(VgB + (size_t)(ktile) * 8192 + w * 1024 + lane * 16, &Vld[bufi][w * 1024]);  \
  } while (0)

  int cur = 0;
  STAGE(0, 0);
  for (int kt = 0; kt <= ktmax; ++kt) {
    if (kt < ktmax) {
      STAGE(cur ^ 1, kt + 1);
      asm volatile("s_waitcnt vmcnt(2)" ::: "memory");  // this tile landed; next in flight
    } else {
      asm volatile("s_waitcnt vmcnt(0)" ::: "memory");
    }
    __builtin_amdgcn_s_barrier();
    const char* Kc = Kl[cur];
    const char* Vc = Vld[cur];

    // QK^T (swapped, permuted rows): s[nt][r] = S[t'=nt*16+r*4+lg][q=lc]
    f32x4 s[8];
    __builtin_amdgcn_s_setprio(1);
#pragma unroll
    for (int nt = 0; nt < 8; nt++) {
      if (kt * 128 + nt * 16 <= q0 + w * 16 + 15) {  // wave-uniform liveness
        s[nt] = (f32x4){0.f, 0.f, 0.f, 0.f};
#pragma unroll
        for (int ks = 0; ks < 4; ks++) {
          bf16x8 kf = *(const bf16x8*)(Kc + nt * 1024 + kro + kswr[ks]);
          s[nt] = mfma16(kf, qf[ks], s[nt]);
        }
      } else {
        s[nt] = (f32x4){-3.0e38f, -3.0e38f, -3.0e38f, -3.0e38f};
      }
    }
    __builtin_amdgcn_s_setprio(0);
    if (kt == ktmax) {  // causal mask on diagonal 128-block
#pragma unroll
      for (int nt = 0; nt < 8; nt++)
#pragma unroll
        for (int r = 0; r < 4; r++)
          if (kt * 128 + nt * 16 + r * 4 + lg > qg) s[nt][r] = -3.0e38f;
    }
    // row max over all 128 t' for q=lc: in-lane 31 fmax + xor16/32
    float v = fmaxf(fmaxf(s[0][0], s[0][1]), fmaxf(s[0][2], s[0][3]));
#pragma unroll
    for (int nt = 1; nt < 8; nt++)
      v = fmaxf(v, fmaxf(fmaxf(s[nt][0], s[nt][1]), fmaxf(s[nt][2], s[nt][3])));
    v = fmaxf(v, __shfl_xor(v, 16));
    v = fmaxf(v, __shfl_xor(v, 32));
    if (__any(v > mrow + 8.0f)) {  // defer-max rescale (rare after first tile)
      float mn = fmaxf(mrow, v);
      float sc = exp2f(mrow - mn);
      mrow = mn;
      lsum *= sc;
#pragma unroll
      for (int r = 0; r < 4; r++) {
        float scr = __shfl(sc, lg * 4 + r);
#pragma unroll
        for (int dt = 0; dt < 8; dt++) o[dt][r] *= scr;
      }
    }
    // exp2 + in-lane fold: pf[nt] = Pfold[q=lc][k32 = nt*4 + lg]
    float pf[8];
    float rs = 0.f;
#pragma unroll
    for (int nt = 0; nt < 8; nt++) {
      float e0 = exp2f(s[nt][0] - mrow);
      float e1 = exp2f(s[nt][1] - mrow);
      float e2 = exp2f(s[nt][2] - mrow);
      float e3 = exp2f(s[nt][3] - mrow);
      pf[nt] = (e0 + e1) + (e2 + e3);
      rs += pf[nt];
    }
    lsum += rs;  // partial (this lane's lg-slice); reduced in epilogue
    bf16x8 af;
#pragma unroll
    for (int j = 0; j < 8; j++) af[j] = (__bf16)pf[j];
    // PV: o[16q][128d] += Pfold * Vm  (8 MFMAs, zero cross-lane)
    __builtin_amdgcn_s_setprio(1);
#pragma unroll
    for (int dt = 0; dt < 8; dt++) {
      bf16x8 vf = *(const bf16x8*)(Vc + dt * 1024 + vbase);
      o[dt] = mfma16(af, vf, o[dt]);
    }
    __builtin_amdgcn_s_setprio(0);
    __builtin_amdgcn_s_barrier();  // all waves done with buf[cur] before overwrite
    cur ^= 1;
  }
  // epilogue: reduce lg-partial row sums, divide, store bf16
  lsum += __shfl_xor(lsum, 16);
  lsum += __shfl_xor(lsum, 32);
  float inv = 1.0f / lsum;
#pragma unroll
  for (int r = 0; r < 4; r++) {
    float invr = __shfl(inv, lg * 4 + r);
    int row = b * 2048 + q0 + w * 16 + lg * 4 + r;
#pragma unroll
    for (int dt = 0; dt < 8; dt++)
      attO[(size_t)row * 2048 + h * 128 + dt * 16 + lc] = (__bf16)(o[dt][r] * invr);
  }
#undef STAGE
}

extern "C" void kernel_launch(void* const* d_in, const int* in_sizes, int n_in,
                              void* d_out, int out_size, void* d_ws, size_t ws_size,
                              hipStream_t stream) {
  const float* X = (const float*)d_in[0];
  const float* Wq = (const float*)d_in[1];
  const float* bq = (const float*)d_in[2];
  const float* Wk = (const float*)d_in[3];
  const float* bk = (const float*)d_in[4];
  const float* Wv = (const float*)d_in[5];
  const float* bv = (const float*)d_in[6];
  const float* Wo = (const float*)d_in[7];
  const float* bo = (const float*)d_in[8];
  char* ws = (char*)d_ws;
  const size_t MB = 1024 * 1024;
  __bf16* Xb     = (__bf16*)(ws + 0);        // 16 MB
  __bf16* WqkvT  = (__bf16*)(ws + 16 * MB);  // 12 MB (3072 x 2048)
  __bf16* WoT    = (__bf16*)(ws + 28 * MB);  // 8 MB
  __bf16* Qbf    = (__bf16*)(ws + 36 * MB);  // 16 MB
  __bf16* Kp     = (__bf16*)(ws + 52 * MB);  // 4 MB
  __bf16* Vp     = (__bf16*)(ws + 56 * MB);  // 4 MB
  __bf16* Vc     = (__bf16*)(ws + 60 * MB);  // 4 MB (reordered V)
  __bf16* aO     = (__bf16*)(ws + 64 * MB);  // 16 MB -> 80 MB total

  convert_f32_bf16<<<4096, 256, 0, stream>>>(X, Xb);
  transpose_w_bf16<<<dim3(64, 64), 256, 0, stream>>>(Wq, WqkvT, 2048, 2048);
  transpose_w_bf16<<<dim3(16, 64), 256, 0, stream>>>(Wk, WqkvT + (size_t)2048 * 2048, 2048, 512);
  transpose_w_bf16<<<dim3(16, 64), 256, 0, stream>>>(Wv, WqkvT + (size_t)2560 * 2048, 2048, 512);
  transpose_w_bf16<<<dim3(64, 64), 256, 0, stream>>>(Wo, WoT, 2048, 2048);

  // fold 1/sqrt(HD) * log2(e) into Q so softmax uses exp2 directly
  float qscale = 1.4426950408889634f * 0.08838834764831845f;
  gemm_qkv<<<dim3(24, 32), 256, 0, stream>>>(Xb, WqkvT, bq, bk, bv, qscale, Qbf, Kp, Vp);

  expand_vc<<<dim3(16, 32), 256, 0, stream>>>(Vp, Vc);
  attn_fwd<<<dim3(32, 16), 512, 0, stream>>>(Qbf, Kp, Vc, aO);

  gemm_bt<1><<<dim3(16, 32), 256, 0, stream>>>(aO, WoT, bo, 1.0f, (float*)d_out, 4096, 2048, 2048);
}

// Round 10
// 278.008 us; speedup vs baseline: 1.1106x; 1.0357x over previous
//
#include <hip/hip_runtime.h>

// GQA forward on MI355X. bf16 MFMA everywhere, f32 accum.
// H=16 heads, G=4 groups, D=2048, HD=128, KV=512, bs=2, s=2048.
// Reference's _expand_kv is a RAW RESHAPE:
//   k[b,h,t',d] = Kp[b, h*128 + t'/16, (t'%4)*128 + d]   (same for v)
// => any 128-t' K/V tile = EIGHT 1KB Kp/Vp rows (8KB unique each).
//
// R10 changes:
//  - ONE fused prep kernel (X->bf16 + 3 weight transposes), 5 launches -> 1.
//  - expand_vc deleted: gemm_qkv V-region epilogue writes scrambled Vc direct.
//  - GEMM LDS seg-XOR swizzle (stage src col ^= row&3; read blk = lg^(lc&3)):
//    kills the 6.29M bank conflicts (32-lane phase had only 4/8 bank-starts).
// Pipeline: prep -> gemm_qkv(Q,Kp,Vc) -> attn -> gemm_bt(O).

#define DEV __device__ __forceinline__

typedef float f32x4 __attribute__((ext_vector_type(4)));
typedef __bf16 bf16x8 __attribute__((ext_vector_type(8)));
typedef __bf16 bf16x4 __attribute__((ext_vector_type(4)));

DEV f32x4 mfma16(bf16x8 a, bf16x8 b, f32x4 c) {
  return __builtin_amdgcn_mfma_f32_16x16x32_bf16(a, b, c, 0, 0, 0);
}

// async global->LDS, 16B/lane. LDS dest = wave-uniform base + lane*16;
// global source address is PER-LANE.
DEV void gld16(const void* gsrc, void* ldst) {
  __builtin_amdgcn_global_load_lds(
      (const __attribute__((address_space(1))) unsigned int*)gsrc,
      (__attribute__((address_space(3))) unsigned int*)ldst, 16, 0, 0);
}

// ---------------- fused prep: X->bf16 + transpose {Wq,Wk,Wv,Wo} ----------------
// blocks [0,4096): convert X (2048 f32 each)
// [4096,8192): Wq->WqkvT rows 0..2047    [8192,9216): Wk->rows 2048..2559
// [9216,10240): Wv->rows 2560..3071      [10240,14336): Wo->WoT
__global__ void prep(const float* __restrict__ X, __bf16* __restrict__ Xb,
                     const float* __restrict__ Wq, const float* __restrict__ Wk,
                     const float* __restrict__ Wv, const float* __restrict__ Wo,
                     __bf16* __restrict__ WqkvT, __bf16* __restrict__ WoT) {
  __shared__ float t[32][33];
  int id = blockIdx.x, tid = threadIdx.x;
  if (id < 4096) {
    size_t i = ((size_t)id * 256 + tid) * 8;
    float4 a = *(const float4*)(X + i);
    float4 b = *(const float4*)(X + i + 4);
    bf16x8 v;
    v[0] = (__bf16)a.x; v[1] = (__bf16)a.y; v[2] = (__bf16)a.z; v[3] = (__bf16)a.w;
    v[4] = (__bf16)b.x; v[5] = (__bf16)b.y; v[6] = (__bf16)b.z; v[7] = (__bf16)b.w;
    *(bf16x8*)(Xb + i) = v;
    return;
  }
  const float* W;
  __bf16* WT;
  int N, nx, ky;
  if (id < 8192) { int r = id - 4096; W = Wq; WT = WqkvT; N = 2048; nx = r & 63; ky = r >> 6; }
  else if (id < 9216) { int r = id - 8192; W = Wk; WT = WqkvT + (size_t)2048 * 2048; N = 512; nx = r & 15; ky = r >> 4; }
  else if (id < 10240) { int r = id - 9216; W = Wv; WT = WqkvT + (size_t)2560 * 2048; N = 512; nx = r & 15; ky = r >> 4; }
  else { int r = id - 10240; W = Wo; WT = WoT; N = 2048; nx = r & 63; ky = r >> 6; }
  int tx = tid & 31, ty = tid >> 5;  // 32x8
  int n0 = nx * 32, k0 = ky * 32;
#pragma unroll
  for (int i = 0; i < 4; i++)
    t[ty + i * 8][tx] = W[(size_t)(k0 + ty + i * 8) * N + n0 + tx];
  __syncthreads();
#pragma unroll
  for (int i = 0; i < 4; i++)
    WT[(size_t)(n0 + ty + i * 8) * 2048 + k0 + tx] = (__bf16)t[tx][ty + i * 8];
}

// ---------------- generic GEMM (O-proj): C = A * Bt^T + bias ----------------
// LDS seg-XOR swizzle: LDS[row][blk] holds global[row][blk ^ (row&3)].
template <int F32OUT>
__global__ __launch_bounds__(256, 3)
void gemm_bt(const __bf16* __restrict__ A, const __bf16* __restrict__ Bt,
             const float* __restrict__ bias, float scale, void* __restrict__ Cout,
             int M, int N, int K) {
  __shared__ __bf16 As[128 * 32];
  __shared__ __bf16 Bs[128 * 32];
  int tid = threadIdx.x, lane = tid & 63, w = tid >> 6;
  int wm = w >> 1, wn = w & 1, lg = lane >> 4, lc = lane & 15;
  int m0 = blockIdx.y * 128, n0 = blockIdx.x * 128;
  int srow = w * 16 + (lane >> 2);
  int scol = ((lane & 3) ^ ((lane >> 2) & 3)) * 8;  // pre-swizzled source block
  const __bf16* Ag = A + (size_t)(m0 + srow) * K + scol;
  const __bf16* Bg = Bt + (size_t)(n0 + srow) * K + scol;
  int rdA = lg ^ (lc & 3);  // swizzled read block
  f32x4 acc[4][4] = {};
  int nk = K >> 5;
  for (int kt = 0; kt < nk; ++kt) {
    if (kt) __syncthreads();
    const __bf16* a = Ag + kt * 32;
    const __bf16* bp = Bg + kt * 32;
    gld16((void*)a, As + (w * 16) * 32);
    gld16((void*)(a + (size_t)64 * K), As + (64 + w * 16) * 32);
    gld16((void*)bp, Bs + (w * 16) * 32);
    gld16((void*)(bp + (size_t)64 * K), Bs + (64 + w * 16) * 32);
    __syncthreads();
    bf16x8 af[4], bf[4];
#pragma unroll
    for (int i = 0; i < 4; i++)
      af[i] = *(const bf16x8*)(As + (wm * 64 + i * 16 + lc) * 32 + rdA * 8);
#pragma unroll
    for (int i = 0; i < 4; i++)
      bf[i] = *(const bf16x8*)(Bs + (wn * 64 + i * 16 + lc) * 32 + rdA * 8);
#pragma unroll
    for (int mi = 0; mi < 4; mi++)
#pragma unroll
      for (int ni = 0; ni < 4; ni++)
        acc[mi][ni] = mfma16(af[mi], bf[ni], acc[mi][ni]);
  }
  float bcol[4];
#pragma unroll
  for (int ni = 0; ni < 4; ni++) bcol[ni] = bias[n0 + wn * 64 + ni * 16 + lc];
#pragma unroll
  for (int mi = 0; mi < 4; mi++)
#pragma unroll
    for (int ni = 0; ni < 4; ni++)
#pragma unroll
      for (int r = 0; r < 4; r++) {
        int row = m0 + wm * 64 + mi * 16 + lg * 4 + r;
        int col = n0 + wn * 64 + ni * 16 + lc;
        float v = (acc[mi][ni][r] + bcol[ni]) * scale;
        if (F32OUT)
          ((float*)Cout)[(size_t)row * N + col] = v;
        else
          ((__bf16*)Cout)[(size_t)row * N + col] = (__bf16)v;
      }
}

// ---------------- fused QKV projection: N=3072 (2048 Q | 512 K | 512 V) ----------------
// V region writes the scrambled/swizzled Vc layout DIRECTLY:
//   Vc[(by*16 + lr/8)*4096 + (d*4 + (seg^((d>>1)&3)))*8 + (lr&7)]
//   where lr = local row (0..127), col = seg*128+d.
__global__ __launch_bounds__(256, 3)
void gemm_qkv(const __bf16* __restrict__ A, const __bf16* __restrict__ Bt,
              const float* __restrict__ bq, const float* __restrict__ bk,
              const float* __restrict__ bv, float qscale,
              __bf16* __restrict__ Qo, __bf16* __restrict__ Ko, __bf16* __restrict__ Vc) {
  const int K = 2048;
  __shared__ __bf16 As[128 * 32];
  __shared__ __bf16 Bs[128 * 32];
  int tid = threadIdx.x, lane = tid & 63, w = tid >> 6;
  int wm = w >> 1, wn = w & 1, lg = lane >> 4, lc = lane & 15;
  int m0 = blockIdx.y * 128, n0 = blockIdx.x * 128;
  int srow = w * 16 + (lane >> 2);
  int scol = ((lane & 3) ^ ((lane >> 2) & 3)) * 8;
  const __bf16* Ag = A + (size_t)(m0 + srow) * K + scol;
  const __bf16* Bg = Bt + (size_t)(n0 + srow) * K + scol;
  int rdA = lg ^ (lc & 3);
  f32x4 acc[4][4] = {};
  for (int kt = 0; kt < 64; ++kt) {
    if (kt) __syncthreads();
    const __bf16* a = Ag + kt * 32;
    const __bf16* bp = Bg + kt * 32;
    gld16((void*)a, As + (w * 16) * 32);
    gld16((void*)(a + (size_t)64 * K), As + (64 + w * 16) * 32);
    gld16((void*)bp, Bs + (w * 16) * 32);
    gld16((void*)(bp + (size_t)64 * K), Bs + (64 + w * 16) * 32);
    __syncthreads();
    bf16x8 af[4], bf[4];
#pragma unroll
    for (int i = 0; i < 4; i++)
      af[i] = *(const bf16x8*)(As + (wm * 64 + i * 16 + lc) * 32 + rdA * 8);
#pragma unroll
    for (int i = 0; i < 4; i++)
      bf[i] = *(const bf16x8*)(Bs + (wn * 64 + i * 16 + lc) * 32 + rdA * 8);
#pragma unroll
    for (int mi = 0; mi < 4; mi++)
#pragma unroll
      for (int ni = 0; ni < 4; ni++)
        acc[mi][ni] = mfma16(af[mi], bf[ni], acc[mi][ni]);
  }
  if (n0 < 2048) {  // Q region
    float bcol[4];
#pragma unroll
    for (int ni = 0; ni < 4; ni++) bcol[ni] = bq[n0 + wn * 64 + ni * 16 + lc];
#pragma unroll
    for (int mi = 0; mi < 4; mi++)
#pragma unroll
      for (int ni = 0; ni < 4; ni++)
#pragma unroll
        for (int r = 0; r < 4; r++) {
          int row = m0 + wm * 64 + mi * 16 + lg * 4 + r;
          int col = n0 + wn * 64 + ni * 16 + lc;
          Qo[(size_t)row * 2048 + col] = (__bf16)((acc[mi][ni][r] + bcol[ni]) * qscale);
        }
  } else if (n0 < 2560) {  // K region -> Kp rows
    int c0 = n0 - 2048;
    float bcol[4];
#pragma unroll
    for (int ni = 0; ni < 4; ni++) bcol[ni] = bk[c0 + wn * 64 + ni * 16 + lc];
#pragma unroll
    for (int mi = 0; mi < 4; mi++)
#pragma unroll
      for (int ni = 0; ni < 4; ni++)
#pragma unroll
        for (int r = 0; r < 4; r++) {
          int row = m0 + wm * 64 + mi * 16 + lg * 4 + r;
          int col = c0 + wn * 64 + ni * 16 + lc;
          Ko[(size_t)row * 512 + col] = (__bf16)(acc[mi][ni][r] + bcol[ni]);
        }
  } else {  // V region -> scrambled Vc, 8B stores (4 rows share kt & d)
    int c0 = n0 - 2560;
    int by = blockIdx.y;  // == bh (b = by>>4, h = by&15)
    float bcol[4];
#pragma unroll
    for (int ni = 0; ni < 4; ni++) bcol[ni] = bv[c0 + wn * 64 + ni * 16 + lc];
#pragma unroll
    for (int mi = 0; mi < 4; mi++) {
      int lrbase = wm * 64 + mi * 16 + lg * 4;  // local row of r=0
      int kt = lrbase >> 3, j0 = lrbase & 7;    // j0 = (lg&1)*4
#pragma unroll
      for (int ni = 0; ni < 4; ni++) {
        int col = c0 + wn * 64 + ni * 16 + lc;
        int seg = col >> 7, d = col & 127;
        bf16x4 pk;
#pragma unroll
        for (int r = 0; r < 4; r++) pk[r] = (__bf16)(acc[mi][ni][r] + bcol[ni]);
        size_t e = (size_t)(by * 16 + kt) * 4096 + (d * 4 + (seg ^ ((d >> 1) & 3))) * 8 + j0;
        *(bf16x4*)(Vc + e) = pk;
      }
    }
  }
}

// ---------------- flash attention, causal, fold-PV, 8-wave QBLK=128 ----------------
// block = 8 waves (512 thr), QBLK=128 (16 q/wave), KVBLK=128, LDS 32KB dbuf.
// Q pre-scaled by log2e/sqrt(128); exp2 softmax, swapped QK^T with permuted
// K rows: s[nt][r] = S[t'=nt*16+r*4+lg][q=lc]. Fold in-lane; PV via Vc.
// Grid (bh=32, slot=16); qt from complementary pairing for uniform makespan.
__global__ __launch_bounds__(512, 4)
void attn_fwd(const __bf16* __restrict__ Qb, const __bf16* __restrict__ Kp,
              const __bf16* __restrict__ VcG, __bf16* __restrict__ attO) {
  __shared__ alignas(16) char Kl[2][8192];   // 8 Kp rows, seg-XOR swizzled
  __shared__ alignas(16) char Vld[2][8192];  // Vc block (pre-swizzled in global)
  int tid = threadIdx.x, lane = tid & 63, w = tid >> 6;  // w = 0..7
  int lg = lane >> 4, lc = lane & 15;
  int slot = (int)blockIdx.y;
  int qt = (slot < 8) ? (15 - 2 * slot) : (2 * slot - 16);  // pairs sum to 17 tiles
  int bh = blockIdx.x, b = bh >> 4, h = bh & 15;
  int q0 = qt * 128;
  int qg = q0 + w * 16 + lc;
  const __bf16* Qrow = Qb + (size_t)(b * 2048 + qg) * 2048 + h * 128 + lg * 8;
  bf16x8 qf[4];
#pragma unroll
  for (int ks = 0; ks < 4; ks++) qf[ks] = *(const bf16x8*)(Qrow + ks * 32);
  asm volatile("s_waitcnt vmcnt(0)" ::: "memory");  // drain Q loads before counted stages
  f32x4 o[8] = {};
  float mrow = -3.0e38f, lsum = 0.f;  // stats for q=lc (lsum = lg-partial)
  const char* KpB = (const char*)Kp + (size_t)(b * 2048 + h * 128) * 1024;  // 1KB rows
  const char* VgB = (const char*)VcG + (size_t)bh * 16 * 8192;
  int ktmax = qt;  // diagonal 128-tile index
  // K stage: src byte offset within a row carries the seg-XOR (seg = lane>>4)
  int ksw = (lane * 16) ^ ((lane >> 4) << 5);
  // K read: per-lane constants
  int seg = lc >> 2;
  int kro = seg * 256;
  int lg16 = lg * 16;
  int kswr[4];
#pragma unroll
  for (int ks = 0; ks < 4; ks++) kswr[ks] = (ks * 64 + lg16) ^ (seg << 5);
  // V read base (swizzle collapses: (dt*16+lc)&6 == lc&6)
  int vbase = lc * 64 + (lg16 ^ ((lc & 6) << 3));

  // 8 waves: wave w stages K row w (1KB) + V KB w. 2 gld16/wave per tile.
#define STAGE(bufi, ktile)                                                             \
  do {                                                                                 \
    gld16(KpB + (size_t)((ktile) * 8 + w) * 1024 + ksw, &Kl[bufi][w * 1024]);          \
    gld16(VgB + (size_t)(ktile) * 8192 + w * 1024 + lane * 16, &Vld[bufi][w * 1024]);  \
  } while (0)

  int cur = 0;
  STAGE(0, 0);
  for (int kt = 0; kt <= ktmax; ++kt) {
    if (kt < ktmax) {
      STAGE(cur ^ 1, kt + 1);
      asm volatile("s_waitcnt vmcnt(2)" ::: "memory");  // this tile landed; next in flight
    } else {
      asm volatile("s_waitcnt vmcnt(0)" ::: "memory");
    }
    __builtin_amdgcn_s_barrier();
    const char* Kc = Kl[cur];
    const char* Vc = Vld[cur];

    // QK^T (swapped, permuted rows): s[nt][r] = S[t'=nt*16+r*4+lg][q=lc]
    f32x4 s[8];
    __builtin_amdgcn_s_setprio(1);
#pragma unroll
    for (int nt = 0; nt < 8; nt++) {
      if (kt * 128 + nt * 16 <= q0 + w * 16 + 15) {  // wave-uniform liveness
        s[nt] = (f32x4){0.f, 0.f, 0.f, 0.f};
#pragma unroll
        for (int ks = 0; ks < 4; ks++) {
          bf16x8 kf = *(const bf16x8*)(Kc + nt * 1024 + kro + kswr[ks]);
          s[nt] = mfma16(kf, qf[ks], s[nt]);
        }
      } else {
        s[nt] = (f32x4){-3.0e38f, -3.0e38f, -3.0e38f, -3.0e38f};
      }
    }
    __builtin_amdgcn_s_setprio(0);
    if (kt == ktmax) {  // causal mask on diagonal 128-block
#pragma unroll
      for (int nt = 0; nt < 8; nt++)
#pragma unroll
        for (int r = 0; r < 4; r++)
          if (kt * 128 + nt * 16 + r * 4 + lg > qg) s[nt][r] = -3.0e38f;
    }
    // row max over all 128 t' for q=lc: in-lane 31 fmax + xor16/32
    float v = fmaxf(fmaxf(s[0][0], s[0][1]), fmaxf(s[0][2], s[0][3]));
#pragma unroll
    for (int nt = 1; nt < 8; nt++)
      v = fmaxf(v, fmaxf(fmaxf(s[nt][0], s[nt][1]), fmaxf(s[nt][2], s[nt][3])));
    v = fmaxf(v, __shfl_xor(v, 16));
    v = fmaxf(v, __shfl_xor(v, 32));
    if (__any(v > mrow + 8.0f)) {  // defer-max rescale (rare after first tile)
      float mn = fmaxf(mrow, v);
      float sc = exp2f(mrow - mn);
      mrow = mn;
      lsum *= sc;
#pragma unroll
      for (int r = 0; r < 4; r++) {
        float scr = __shfl(sc, lg * 4 + r);
#pragma unroll
        for (int dt = 0; dt < 8; dt++) o[dt][r] *= scr;
      }
    }
    // exp2 + in-lane fold: pf[nt] = Pfold[q=lc][k32 = nt*4 + lg]
    float pf[8];
    float rs = 0.f;
#pragma unroll
    for (int nt = 0; nt < 8; nt++) {
      float e0 = exp2f(s[nt][0] - mrow);
      float e1 = exp2f(s[nt][1] - mrow);
      float e2 = exp2f(s[nt][2] - mrow);
      float e3 = exp2f(s[nt][3] - mrow);
      pf[nt] = (e0 + e1) + (e2 + e3);
      rs += pf[nt];
    }
    lsum += rs;  // partial (this lane's lg-slice); reduced in epilogue
    bf16x8 af;
#pragma unroll
    for (int j = 0; j < 8; j++) af[j] = (__bf16)pf[j];
    // PV: o[16q][128d] += Pfold * Vm  (8 MFMAs, zero cross-lane)
    __builtin_amdgcn_s_setprio(1);
#pragma unroll
    for (int dt = 0; dt < 8; dt++) {
      bf16x8 vf = *(const bf16x8*)(Vc + dt * 1024 + vbase);
      o[dt] = mfma16(af, vf, o[dt]);
    }
    __builtin_amdgcn_s_setprio(0);
    __builtin_amdgcn_s_barrier();  // all waves done with buf[cur] before overwrite
    cur ^= 1;
  }
  // epilogue: reduce lg-partial row sums, divide, store bf16
  lsum += __shfl_xor(lsum, 16);
  lsum += __shfl_xor(lsum, 32);
  float inv = 1.0f / lsum;
#pragma unroll
  for (int r = 0; r < 4; r++) {
    float invr = __shfl(inv, lg * 4 + r);
    int row = b * 2048 + q0 + w * 16 + lg * 4 + r;
#pragma unroll
    for (int dt = 0; dt < 8; dt++)
      attO[(size_t)row * 2048 + h * 128 + dt * 16 + lc] = (__bf16)(o[dt][r] * invr);
  }
#undef STAGE
}

extern "C" void kernel_launch(void* const* d_in, const int* in_sizes, int n_in,
                              void* d_out, int out_size, void* d_ws, size_t ws_size,
                              hipStream_t stream) {
  const float* X = (const float*)d_in[0];
  const float* Wq = (const float*)d_in[1];
  const float* bq = (const float*)d_in[2];
  const float* Wk = (const float*)d_in[3];
  const float* bk = (const float*)d_in[4];
  const float* Wv = (const float*)d_in[5];
  const float* bv = (const float*)d_in[6];
  const float* Wo = (const float*)d_in[7];
  const float* bo = (const float*)d_in[8];
  char* ws = (char*)d_ws;
  const size_t MB = 1024 * 1024;
  __bf16* Xb     = (__bf16*)(ws + 0);        // 16 MB
  __bf16* WqkvT  = (__bf16*)(ws + 16 * MB);  // 12 MB (3072 x 2048)
  __bf16* WoT    = (__bf16*)(ws + 28 * MB);  // 8 MB
  __bf16* Qbf    = (__bf16*)(ws + 36 * MB);  // 16 MB
  __bf16* Kp     = (__bf16*)(ws + 52 * MB);  // 4 MB
  __bf16* Vc     = (__bf16*)(ws + 56 * MB);  // 4 MB (scrambled V)
  __bf16* aO     = (__bf16*)(ws + 60 * MB);  // 16 MB -> 76 MB total

  prep<<<14336, 256, 0, stream>>>(X, Xb, Wq, Wk, Wv, Wo, WqkvT, WoT);

  // fold 1/sqrt(HD) * log2(e) into Q so softmax uses exp2 directly
  float qscale = 1.4426950408889634f * 0.08838834764831845f;
  gemm_qkv<<<dim3(24, 32), 256, 0, stream>>>(Xb, WqkvT, bq, bk, bv, qscale, Qbf, Kp, Vc);

  attn_fwd<<<dim3(32, 16), 512, 0, stream>>>(Qbf, Kp, Vc, aO);

  gemm_bt<1><<<dim3(16, 32), 256, 0, stream>>>(aO, WoT, bo, 1.0f, (float*)d_out, 4096, 2048, 2048);
}